// Round 1
// baseline (331.413 us; speedup 1.0000x reference)
//
#include <hip/hip_runtime.h>
#include <hip/hip_bf16.h>
#include <math.h>

// LSTM cell fused kernel, MI355X gfx950.
// B=65536, I=128, H=256, O=256, K=I+H=384.
// out = [log_softmax(combined@w_i2o.T+b_i2o) (B*256), new_hidden (B*256)]

typedef __attribute__((ext_vector_type(8))) short bf16x8;   // 8 bf16 = 4 VGPRs
typedef __attribute__((ext_vector_type(4))) float f32x4;

#define BM   64     // rows per block
#define LDA  392    // padded LDS row stride in bf16 elems (384+8): 2-way-only bank aliasing, 16B aligned
#define NW1  393216 // 1024*384
#define NW2  98304  // 256*384

__device__ __forceinline__ unsigned short f2bf(float f) {
    union { __hip_bfloat16 h; unsigned short u; } cv;
    cv.h = __float2bfloat16(f);
    return cv.u;
}
__device__ __forceinline__ float bf2f(unsigned short u) {
    union { __hip_bfloat16 h; unsigned short u; } cv;
    cv.u = u;
    return __bfloat162float(cv.h);
}
__device__ __forceinline__ float fsigmoid(float x) {
    return 1.0f / (1.0f + __expf(-x));
}
__device__ __forceinline__ float ftanh(float x) {
    // tanh(x) = 1 - 2/(exp(2x)+1); robust at +-inf overflow of __expf
    return 1.0f - 2.0f / (__expf(2.0f * x) + 1.0f);
}

// Convert fp32 weights -> bf16 into workspace. Runs every launch (ws is re-poisoned).
__global__ void conv_w(const float* __restrict__ w1, const float* __restrict__ w2,
                       unsigned short* __restrict__ wb) {
    int idx = blockIdx.x * 256 + threadIdx.x;   // per-float4; total (NW1+NW2)/4 = 122880
    const int n1 = NW1 / 4;
    float4 v;
    if (idx < n1) v = ((const float4*)w1)[idx];
    else          v = ((const float4*)w2)[idx - n1];
    ushort4 u;
    u.x = f2bf(v.x); u.y = f2bf(v.y); u.z = f2bf(v.z); u.w = f2bf(v.w);
    ((ushort4*)wb)[idx] = u;
}

__launch_bounds__(256, 2)
__global__ void lstm_fused(const float* __restrict__ input,    // [B,128]
                           const float* __restrict__ hidden,   // [B,256]
                           const unsigned short* __restrict__ w1b, // bf16 [1024][384]
                           const unsigned short* __restrict__ w2b, // bf16 [256][384]
                           const float* __restrict__ b1,       // [1024]
                           const float* __restrict__ b2,       // [256]
                           float* __restrict__ out_ls,         // [B,256]
                           float* __restrict__ out_nh)         // [B,256]
{
    __shared__ unsigned short A[BM * LDA];      // combined tile, bf16
    __shared__ float red_m[4][BM];
    __shared__ float red_s[4][BM];

    const int tid  = threadIdx.x;
    const int wave = tid >> 6;
    const int lane = tid & 63;
    const int l15  = lane & 15;
    const int quad = lane >> 4;
    const size_t r0 = (size_t)blockIdx.x * BM;

    // ---- stage combined [64 x 384] fp32 -> bf16 LDS ----
    for (int idx = tid; idx < BM * 96; idx += 256) {
        int row = idx / 96, c4 = idx % 96;
        float4 v = (c4 < 32)
            ? ((const float4*)(input  + (r0 + row) * 128))[c4]
            : ((const float4*)(hidden + (r0 + row) * 256))[c4 - 32];
        ushort4 u;
        u.x = f2bf(v.x); u.y = f2bf(v.y); u.z = f2bf(v.z); u.w = f2bf(v.w);
        *(ushort4*)&A[row * LDA + c4 * 4] = u;
    }
    __syncthreads();

    // A-operand per-lane base: A[m = l15][k = quad*8 + j]
    const unsigned short* ap0 = &A[l15 * LDA + quad * 8];

    // 5 column phases: 0..3 = gate quadrant-interleaved (j ranges), 4 = logits.
    for (int phase = 0; phase < 5; ++phase) {
        f32x4 acc[4][4];
        #pragma unroll
        for (int i = 0; i < 4; ++i)
            #pragma unroll
            for (int j = 0; j < 4; ++j)
                acc[i][j] = (f32x4){0.f, 0.f, 0.f, 0.f};

        // B-operand per-lane base pointers (lane holds W[n = col][k = quad*8+j])
        const unsigned short* bp[4];
        if (phase < 4) {
            int j0 = phase * 64 + wave * 16;
            #pragma unroll
            for (int q = 0; q < 4; ++q)
                bp[q] = w1b + (size_t)(q * 256 + j0 + l15) * 384 + quad * 8;
        } else {
            #pragma unroll
            for (int nt = 0; nt < 4; ++nt)
                bp[nt] = w2b + (size_t)(wave * 64 + nt * 16 + l15) * 384 + quad * 8;
        }

        #pragma unroll
        for (int kk = 0; kk < 384; kk += 32) {
            bf16x8 a[4], b[4];
            #pragma unroll
            for (int mt = 0; mt < 4; ++mt)
                a[mt] = *(const bf16x8*)(ap0 + mt * 16 * LDA + kk);
            #pragma unroll
            for (int nt = 0; nt < 4; ++nt)
                b[nt] = *(const bf16x8*)(bp[nt] + kk);
            #pragma unroll
            for (int mt = 0; mt < 4; ++mt)
                #pragma unroll
                for (int nt = 0; nt < 4; ++nt)
                    acc[mt][nt] = __builtin_amdgcn_mfma_f32_16x16x32_bf16(
                        a[mt], b[nt], acc[mt][nt], 0, 0, 0);
        }

        if (phase < 4) {
            // acc[mt][q][r] = gates[row = mt*16+quad*4+r][q*256 + j], j = phase*64+wave*16+l15
            int j = phase * 64 + wave * 16 + l15;
            float bq0 = b1[j], bq1 = b1[256 + j], bq2 = b1[512 + j], bq3 = b1[768 + j];
            #pragma unroll
            for (int mt = 0; mt < 4; ++mt) {
                #pragma unroll
                for (int r = 0; r < 4; ++r) {
                    int rowl = mt * 16 + quad * 4 + r;
                    float hprev = bf2f(A[rowl * LDA + 128 + j]);
                    float hv  = ftanh(acc[mt][0][r] + bq0);
                    float igv = fsigmoid(acc[mt][1][r] + bq1);
                    float fgv = fsigmoid(acc[mt][2][r] + bq2);
                    float ogv = fsigmoid(acc[mt][3][r] + bq3);
                    out_nh[(r0 + rowl) * 256 + j] = ogv * ftanh(fgv * hprev + igv * hv);
                }
            }
        } else {
            // acc[mt][nt][r] = logits[row][col = wave*64 + nt*16 + l15]
            float bo[4];
            #pragma unroll
            for (int nt = 0; nt < 4; ++nt) bo[nt] = b2[wave * 64 + nt * 16 + l15];
            #pragma unroll
            for (int mt = 0; mt < 4; ++mt)
                #pragma unroll
                for (int nt = 0; nt < 4; ++nt)
                    #pragma unroll
                    for (int r = 0; r < 4; ++r)
                        acc[mt][nt][r] += bo[nt];

            // per-row max: reduce over nt in-lane, then over l15 via xor-butterfly (stays in quad)
            float pm[4][4], ps[4][4];
            #pragma unroll
            for (int mt = 0; mt < 4; ++mt)
                #pragma unroll
                for (int r = 0; r < 4; ++r) {
                    float m = acc[mt][0][r];
                    #pragma unroll
                    for (int nt = 1; nt < 4; ++nt) m = fmaxf(m, acc[mt][nt][r]);
                    pm[mt][r] = m;
                }
            #pragma unroll
            for (int mask = 1; mask < 16; mask <<= 1)
                #pragma unroll
                for (int mt = 0; mt < 4; ++mt)
                    #pragma unroll
                    for (int r = 0; r < 4; ++r)
                        pm[mt][r] = fmaxf(pm[mt][r], __shfl_xor(pm[mt][r], mask, 64));
            // per-wave sumexp wrt wave max
            #pragma unroll
            for (int mt = 0; mt < 4; ++mt)
                #pragma unroll
                for (int r = 0; r < 4; ++r) {
                    float s = 0.f;
                    #pragma unroll
                    for (int nt = 0; nt < 4; ++nt)
                        s += __expf(acc[mt][nt][r] - pm[mt][r]);
                    ps[mt][r] = s;
                }
            #pragma unroll
            for (int mask = 1; mask < 16; mask <<= 1)
                #pragma unroll
                for (int mt = 0; mt < 4; ++mt)
                    #pragma unroll
                    for (int r = 0; r < 4; ++r)
                        ps[mt][r] += __shfl_xor(ps[mt][r], mask, 64);

            if (l15 == 0) {
                #pragma unroll
                for (int mt = 0; mt < 4; ++mt)
                    #pragma unroll
                    for (int r = 0; r < 4; ++r) {
                        int rowl = mt * 16 + quad * 4 + r;
                        red_m[wave][rowl] = pm[mt][r];
                        red_s[wave][rowl] = ps[mt][r];
                    }
            }
            __syncthreads();
            #pragma unroll
            for (int mt = 0; mt < 4; ++mt)
                #pragma unroll
                for (int r = 0; r < 4; ++r) {
                    int rowl = mt * 16 + quad * 4 + r;
                    float M = red_m[0][rowl];
                    #pragma unroll
                    for (int w = 1; w < 4; ++w) M = fmaxf(M, red_m[w][rowl]);
                    float S = 0.f;
                    #pragma unroll
                    for (int w = 0; w < 4; ++w)
                        S += red_s[w][rowl] * __expf(red_m[w][rowl] - M);
                    float lz = M + logf(S);
                    #pragma unroll
                    for (int nt = 0; nt < 4; ++nt)
                        out_ls[(r0 + rowl) * 256 + wave * 64 + nt * 16 + l15] =
                            acc[mt][nt][r] - lz;
                }
        }
    }
}

extern "C" void kernel_launch(void* const* d_in, const int* in_sizes, int n_in,
                              void* d_out, int out_size, void* d_ws, size_t ws_size,
                              hipStream_t stream) {
    const float* input  = (const float*)d_in[0];
    const float* hidden = (const float*)d_in[1];
    const float* w1     = (const float*)d_in[2];
    const float* b1     = (const float*)d_in[3];
    const float* w2     = (const float*)d_in[4];
    const float* b2     = (const float*)d_in[5];
    float* out = (float*)d_out;
    unsigned short* wb = (unsigned short*)d_ws;   // needs 983040 B

    conv_w<<<dim3((NW1 + NW2) / 4 / 256), dim3(256), 0, stream>>>(w1, w2, wb);
    lstm_fused<<<dim3(65536 / BM), dim3(256), 0, stream>>>(
        input, hidden, wb, wb + NW1, b1, b2,
        out, out + (size_t)65536 * 256);
}